// Round 1
// baseline (1111.488 us; speedup 1.0000x reference)
//
#include <hip/hip_runtime.h>
#include <math.h>

#define BSZ 1024
#define TS 7
#define DD 1024
#define HH 1024
#define NG 4096  // 4*H

__device__ __forceinline__ float sigm_(float x) { return 1.f / (1.f + __expf(-x)); }
__device__ __forceinline__ float tanh_(float x) { return 1.f - 2.f / (__expf(2.f * x) + 1.f); }

// ---------------------------------------------------------------------------
// Kernel A: per-batch covariance stats.
//   cov_temp[b,t]  = relu( (S_xy - S_x*S_y/D) / TS )   (sums over d)
//   cov_chan[b,d]  = relu( (S_xy - S_x*S_y/TS) / D )   (sums over t)
// One block per b; each thread owns 4 consecutive d (float4), all 7 t in regs.
// ---------------------------------------------------------------------------
__global__ __launch_bounds__(256) void cov_kernel(
    const float* __restrict__ x, const float* __restrict__ xsh,
    float* __restrict__ covT, float* __restrict__ covC) {
  const int b = blockIdx.x, tid = threadIdx.x;
  const float4* xb = (const float4*)(x + (size_t)b * TS * DD);
  const float4* yb = (const float4*)(xsh + (size_t)b * TS * DD);
  float4 xv[TS], yv[TS];
#pragma unroll
  for (int t = 0; t < TS; t++) {
    xv[t] = xb[t * 256 + tid];
    yv[t] = yb[t * 256 + tid];
  }
  // channel covariance for this thread's 4 d's
  float cc[4];
#pragma unroll
  for (int q = 0; q < 4; q++) {
    float sx = 0.f, sy = 0.f, sxy = 0.f;
#pragma unroll
    for (int t = 0; t < TS; t++) {
      float a = ((const float*)&xv[t])[q];
      float c = ((const float*)&yv[t])[q];
      sx += a; sy += c; sxy += a * c;
    }
    float v = (sxy - sx * sy * (1.f / TS)) * (1.f / DD);
    cc[q] = v > 0.f ? v : 0.f;
  }
  *(float4*)&covC[(size_t)b * DD + tid * 4] = make_float4(cc[0], cc[1], cc[2], cc[3]);

  // temporal covariance partials (sum over d)
  float psx[TS], psy[TS], psxy[TS];
#pragma unroll
  for (int t = 0; t < TS; t++) {
    float4 a = xv[t], c = yv[t];
    psx[t] = a.x + a.y + a.z + a.w;
    psy[t] = c.x + c.y + c.z + c.w;
    psxy[t] = a.x * c.x + a.y * c.y + a.z * c.z + a.w * c.w;
  }
#pragma unroll
  for (int t = 0; t < TS; t++) {
    for (int m = 32; m >= 1; m >>= 1) {
      psx[t] += __shfl_xor(psx[t], m);
      psy[t] += __shfl_xor(psy[t], m);
      psxy[t] += __shfl_xor(psxy[t], m);
    }
  }
  __shared__ float red[3][4][TS];
  const int wave = tid >> 6, lane = tid & 63;
  if (lane == 0) {
#pragma unroll
    for (int t = 0; t < TS; t++) {
      red[0][wave][t] = psx[t];
      red[1][wave][t] = psy[t];
      red[2][wave][t] = psxy[t];
    }
  }
  __syncthreads();
  if (tid < TS) {
    float sx = red[0][0][tid] + red[0][1][tid] + red[0][2][tid] + red[0][3][tid];
    float sy = red[1][0][tid] + red[1][1][tid] + red[1][2][tid] + red[1][3][tid];
    float sxy = red[2][0][tid] + red[2][1][tid] + red[2][2][tid] + red[2][3][tid];
    float v = (sxy - sx * sy * (1.f / DD)) * (1.f / TS);
    covT[b * TS + tid] = v > 0.f ? v : 0.f;
  }
}

// ---------------------------------------------------------------------------
// Kernel B: fused GEMM + LSTM gate epilogue.
//   MODE 0: acc = covC @ W_ih^T tile  -> store M, then t=0 gates (h0=c0=0)
//   MODE 1: acc = h_{t-1} @ W_hh^T tile; g = acc + covT[b,t]*M[b,:] + bias
// Tile: BM=64 rows(b) x 32 j x 4 gates (eff. 128 cols), BK=32, 256 threads.
// Gate-minor col layout n = jj*4+g so each lane owns all 4 gates of one j.
// ---------------------------------------------------------------------------
template <int MODE>
__global__ __launch_bounds__(256, 2) void lstm_gemm(
    const float* __restrict__ Ap, int lda, const float* __restrict__ Wp,
    const float* __restrict__ covT, int t, const float* __restrict__ Min,
    float* __restrict__ Mout, const float* __restrict__ b_ih,
    const float* __restrict__ b_hh, float* __restrict__ cbuf,
    float* __restrict__ hout)  // hout = h_all + t*HH, row stride TS*HH
{
  __shared__ float As[32][68];    // [k][row]
  __shared__ float Ws[32][132];   // [k][n], n = jj*4+g
  const int tid = threadIdx.x;
  const int jb = blockIdx.x;   // 0..31
  const int rb = blockIdx.y;   // 0..15
  const int rowBase = rb * 64;
  const int jBase = jb * 32;
  const int tr = tid >> 5;     // 0..7 -> rows tr*8..tr*8+7
  const int tc = tid & 31;     // 0..31 -> j = jBase+tc, gates 0..3
  const int srow = tid >> 3;   // staging: 0..31
  const int skq = tid & 7;

  float acc[8][4] = {};

  for (int kt = 0; kt < 32; kt++) {
    const int k0 = kt * 32;
    // ---- stage A (64x32) ----
    {
      float4 v0 = *(const float4*)&Ap[(size_t)(rowBase + srow) * lda + k0 + skq * 4];
      float4 v1 = *(const float4*)&Ap[(size_t)(rowBase + srow + 32) * lda + k0 + skq * 4];
      As[skq * 4 + 0][srow] = v0.x; As[skq * 4 + 1][srow] = v0.y;
      As[skq * 4 + 2][srow] = v0.z; As[skq * 4 + 3][srow] = v0.w;
      As[skq * 4 + 0][srow + 32] = v1.x; As[skq * 4 + 1][srow + 32] = v1.y;
      As[skq * 4 + 2][srow + 32] = v1.z; As[skq * 4 + 3][srow + 32] = v1.w;
    }
    // ---- stage W (128x32), n=jj*4+g -> global row g*HH + jBase + jj ----
#pragma unroll
    for (int i = 0; i < 4; i++) {
      int c = tid + 256 * i;
      int n = c >> 3, kq = c & 7;
      int grow = (n & 3) * HH + jBase + (n >> 2);
      float4 v = *(const float4*)&Wp[(size_t)grow * DD + k0 + kq * 4];
      Ws[kq * 4 + 0][n] = v.x; Ws[kq * 4 + 1][n] = v.y;
      Ws[kq * 4 + 2][n] = v.z; Ws[kq * 4 + 3][n] = v.w;
    }
    __syncthreads();
#pragma unroll 8
    for (int kk = 0; kk < 32; kk++) {
      float4 w = *(const float4*)&Ws[kk][tc * 4];
      float4 a0 = *(const float4*)&As[kk][tr * 8];
      float4 a1 = *(const float4*)&As[kk][tr * 8 + 4];
      const float ar[8] = {a0.x, a0.y, a0.z, a0.w, a1.x, a1.y, a1.z, a1.w};
#pragma unroll
      for (int r = 0; r < 8; r++) {
        acc[r][0] += ar[r] * w.x;
        acc[r][1] += ar[r] * w.y;
        acc[r][2] += ar[r] * w.z;
        acc[r][3] += ar[r] * w.w;
      }
    }
    __syncthreads();
  }

  // ---- epilogue: LSTM gates ----
  const int jj = jBase + tc;
  const float bi0 = b_ih[jj] + b_hh[jj];
  const float bi1 = b_ih[HH + jj] + b_hh[HH + jj];
  const float bi2 = b_ih[2 * HH + jj] + b_hh[2 * HH + jj];
  const float bi3 = b_ih[3 * HH + jj] + b_hh[3 * HH + jj];
#pragma unroll
  for (int r = 0; r < 8; r++) {
    const int b = rowBase + tr * 8 + r;
    const float a = covT[b * TS + t];
    float gi, gf, gg, go;
    if (MODE == 0) {
      Mout[(size_t)b * NG + jj] = acc[r][0];
      Mout[(size_t)b * NG + HH + jj] = acc[r][1];
      Mout[(size_t)b * NG + 2 * HH + jj] = acc[r][2];
      Mout[(size_t)b * NG + 3 * HH + jj] = acc[r][3];
      gi = a * acc[r][0] + bi0;
      gf = a * acc[r][1] + bi1;
      gg = a * acc[r][2] + bi2;
      go = a * acc[r][3] + bi3;
    } else {
      gi = acc[r][0] + a * Min[(size_t)b * NG + jj] + bi0;
      gf = acc[r][1] + a * Min[(size_t)b * NG + HH + jj] + bi1;
      gg = acc[r][2] + a * Min[(size_t)b * NG + 2 * HH + jj] + bi2;
      go = acc[r][3] + a * Min[(size_t)b * NG + 3 * HH + jj] + bi3;
    }
    const float i_ = sigm_(gi), f_ = sigm_(gf), g_ = tanh_(gg), o_ = sigm_(go);
    float cn;
    if (MODE == 0)
      cn = i_ * g_;
    else
      cn = f_ * cbuf[(size_t)b * HH + jj] + i_ * g_;
    cbuf[(size_t)b * HH + jj] = cn;
    hout[(size_t)b * TS * HH + jj] = o_ * tanh_(cn);
  }
}

// ---------------------------------------------------------------------------
// Kernel C: softmax over t (axis=1) + temporal attention, one pass over h.
// One block per b; thread owns 4 j-columns, all 7 t in registers.
// ---------------------------------------------------------------------------
__global__ __launch_bounds__(256) void finale(
    const float* __restrict__ h_all, const float* __restrict__ attn_W,
    const float* __restrict__ attn_b, float* __restrict__ out) {
  const int b = blockIdx.x, tid = threadIdx.x;
  const float4* hb = (const float4*)(h_all + (size_t)b * TS * HH);
  float4 v[TS];
#pragma unroll
  for (int t = 0; t < TS; t++) v[t] = hb[t * 256 + tid];
  const float4 aw = ((const float4*)attn_W)[tid];

  float4 outv[TS];
#pragma unroll
  for (int q = 0; q < 4; q++) {
    float m = -1e30f;
#pragma unroll
    for (int t = 0; t < TS; t++) m = fmaxf(m, ((const float*)&v[t])[q]);
    float e[TS], s = 0.f;
#pragma unroll
    for (int t = 0; t < TS; t++) {
      e[t] = __expf(((const float*)&v[t])[q] - m);
      s += e[t];
    }
    const float inv = 1.f / s;
#pragma unroll
    for (int t = 0; t < TS; t++) ((float*)&outv[t])[q] = e[t] * inv;
  }
#pragma unroll
  for (int t = 0; t < TS; t++)
    ((float4*)out)[(size_t)b * TS * 256 + t * 256 + tid] = outv[t];

  // temporal attention: sigmoid( sum_j tanh(h[b,t,j])*attn_W[j] + attn_b )
  float pt[TS];
#pragma unroll
  for (int t = 0; t < TS; t++) {
    pt[t] = tanh_(v[t].x) * aw.x + tanh_(v[t].y) * aw.y + tanh_(v[t].z) * aw.z +
            tanh_(v[t].w) * aw.w;
  }
#pragma unroll
  for (int t = 0; t < TS; t++)
    for (int m = 32; m >= 1; m >>= 1) pt[t] += __shfl_xor(pt[t], m);
  __shared__ float red[4][TS];
  const int wave = tid >> 6, lane = tid & 63;
  if (lane == 0) {
#pragma unroll
    for (int t = 0; t < TS; t++) red[wave][t] = pt[t];
  }
  __syncthreads();
  if (tid < TS) {
    float s = red[0][tid] + red[1][tid] + red[2][tid] + red[3][tid];
    out[(size_t)BSZ * TS * HH + b * TS + tid] = sigm_(s + attn_b[0]);
  }
}

// ---------------------------------------------------------------------------
extern "C" void kernel_launch(void* const* d_in, const int* in_sizes, int n_in,
                              void* d_out, int out_size, void* d_ws,
                              size_t ws_size, hipStream_t stream) {
  const float* x = (const float*)d_in[0];
  const float* xsh = (const float*)d_in[1];
  const float* W_ih = (const float*)d_in[2];
  const float* W_hh = (const float*)d_in[3];
  const float* b_ih = (const float*)d_in[4];
  const float* b_hh = (const float*)d_in[5];
  const float* attn_W = (const float*)d_in[6];
  const float* attn_b = (const float*)d_in[7];
  float* out = (float*)d_out;
  float* ws = (float*)d_ws;

  float* covT = ws;                    // 7168 (pad to 8192)
  float* covC = ws + 8192;             // 1048576
  float* Mbuf = covC + 1048576;        // 4194304
  float* cbuf = Mbuf + 4194304;        // 1048576
  float* h_all = cbuf + 1048576;       // 7340032   total ~54.6 MB

  cov_kernel<<<dim3(BSZ), dim3(256), 0, stream>>>(x, xsh, covT, covC);
  lstm_gemm<0><<<dim3(32, 16), dim3(256), 0, stream>>>(
      covC, DD, W_ih, covT, 0, nullptr, Mbuf, b_ih, b_hh, cbuf, h_all);
  for (int t = 1; t < TS; t++) {
    lstm_gemm<1><<<dim3(32, 16), dim3(256), 0, stream>>>(
        h_all + (size_t)(t - 1) * HH, TS * HH, W_hh, covT, t, Mbuf, nullptr,
        b_ih, b_hh, cbuf, h_all + (size_t)t * HH);
  }
  finale<<<dim3(BSZ), dim3(256), 0, stream>>>(h_all, attn_W, attn_b, out);
}

// Round 5
// 345.577 us; speedup vs baseline: 3.2163x; 3.2163x over previous
//
#include <hip/hip_runtime.h>
#include <math.h>

#define BSZ 1024
#define TS 7
#define DD 1024
#define HH 1024
#define NG 4096  // 4*H

typedef _Float16 f16x8 __attribute__((ext_vector_type(8)));
typedef _Float16 f16x4 __attribute__((ext_vector_type(4)));
typedef float f32x4 __attribute__((ext_vector_type(4)));

__device__ __forceinline__ float sigm_(float x) { return 1.f / (1.f + __expf(-x)); }
__device__ __forceinline__ float tanh_(float x) { return 1.f - 2.f / (__expf(2.f * x) + 1.f); }

__device__ __forceinline__ void gload16(const _Float16* g, _Float16* l) {
  __builtin_amdgcn_global_load_lds(
      (const __attribute__((address_space(1))) void*)g,
      (__attribute__((address_space(3))) void*)l, 16, 0, 0);
}

// ---------------------------------------------------------------------------
// fp32 -> fp16 weight conversion (grid-stride, float4 -> f16x4)
// ---------------------------------------------------------------------------
__global__ __launch_bounds__(256) void f32_to_f16(const float* __restrict__ in,
                                                  _Float16* __restrict__ out,
                                                  int n4) {
  for (int i = blockIdx.x * 256 + threadIdx.x; i < n4; i += gridDim.x * 256) {
    float4 v = ((const float4*)in)[i];
    f16x4 o;
    o[0] = (_Float16)v.x; o[1] = (_Float16)v.y;
    o[2] = (_Float16)v.z; o[3] = (_Float16)v.w;
    ((f16x4*)out)[i] = o;
  }
}

// ---------------------------------------------------------------------------
// Kernel A: per-batch covariance stats. covT fp32 [B][TS]; covC fp16 [B][DD].
// ---------------------------------------------------------------------------
__global__ __launch_bounds__(256) void cov_kernel(
    const float* __restrict__ x, const float* __restrict__ xsh,
    float* __restrict__ covT, _Float16* __restrict__ covC16) {
  const int b = blockIdx.x, tid = threadIdx.x;
  const float4* xb = (const float4*)(x + (size_t)b * TS * DD);
  const float4* yb = (const float4*)(xsh + (size_t)b * TS * DD);
  float4 xv[TS], yv[TS];
#pragma unroll
  for (int t = 0; t < TS; t++) {
    xv[t] = xb[t * 256 + tid];
    yv[t] = yb[t * 256 + tid];
  }
  f16x4 cc;
#pragma unroll
  for (int q = 0; q < 4; q++) {
    float sx = 0.f, sy = 0.f, sxy = 0.f;
#pragma unroll
    for (int t = 0; t < TS; t++) {
      float a = ((const float*)&xv[t])[q];
      float c = ((const float*)&yv[t])[q];
      sx += a; sy += c; sxy += a * c;
    }
    float v = (sxy - sx * sy * (1.f / TS)) * (1.f / DD);
    cc[q] = (_Float16)(v > 0.f ? v : 0.f);
  }
  *(f16x4*)&covC16[(size_t)b * DD + tid * 4] = cc;

  float psx[TS], psy[TS], psxy[TS];
#pragma unroll
  for (int t = 0; t < TS; t++) {
    float4 a = xv[t], c = yv[t];
    psx[t] = a.x + a.y + a.z + a.w;
    psy[t] = c.x + c.y + c.z + c.w;
    psxy[t] = a.x * c.x + a.y * c.y + a.z * c.z + a.w * c.w;
  }
#pragma unroll
  for (int t = 0; t < TS; t++) {
    for (int m = 32; m >= 1; m >>= 1) {
      psx[t] += __shfl_xor(psx[t], m);
      psy[t] += __shfl_xor(psy[t], m);
      psxy[t] += __shfl_xor(psxy[t], m);
    }
  }
  __shared__ float red[3][4][TS];
  const int wave = tid >> 6, lane = tid & 63;
  if (lane == 0) {
#pragma unroll
    for (int t = 0; t < TS; t++) {
      red[0][wave][t] = psx[t];
      red[1][wave][t] = psy[t];
      red[2][wave][t] = psxy[t];
    }
  }
  __syncthreads();
  if (tid < TS) {
    float sx = red[0][0][tid] + red[0][1][tid] + red[0][2][tid] + red[0][3][tid];
    float sy = red[1][0][tid] + red[1][1][tid] + red[1][2][tid] + red[1][3][tid];
    float sxy = red[2][0][tid] + red[2][1][tid] + red[2][2][tid] + red[2][3][tid];
    float v = (sxy - sx * sy * (1.f / DD)) * (1.f / TS);
    covT[b * TS + tid] = v > 0.f ? v : 0.f;
  }
}

// ---------------------------------------------------------------------------
// Kernel B: fp16 MFMA GEMM, C[1024 x 4096] = A[1024 x 1024] * W[4096 x 1024]^T
// BM=64 BN=128 BK=64, 256 thr (4 waves), wave tile 64x32 = 4m x 2n frags of
// 16x16x32_f16. global_load_lds width-16 staging, linear LDS, 2-barrier loop.
// OutT: _Float16 for M (tiny magnitudes), float for G (precision hedge).
// ---------------------------------------------------------------------------
template <typename OutT>
__global__ __launch_bounds__(256) void gemm_f16(
    const _Float16* __restrict__ A, int lda, const _Float16* __restrict__ W,
    OutT* __restrict__ Out) {
  __shared__ _Float16 As[64 * 64];   // [row][k] 8 KB
  __shared__ _Float16 Bs[128 * 64];  // [col][k] 16 KB
  const int tid = threadIdx.x;
  const int wave = tid >> 6, lane = tid & 63;
  const int l15 = lane & 15, lhi = lane >> 4;
  const int rowBase = blockIdx.y * 64;
  const int colBase = blockIdx.x * 128;
  const int sRow = tid >> 3;        // 0..31
  const int sCol = (tid & 7) * 8;   // k offset, 16B granular
  _Float16* ldsA = &As[(tid & ~63) * 8];   // wave-uniform base (wave*512)
  _Float16* ldsB = &Bs[(tid & ~63) * 8];
  f32x4 acc[4][2] = {};

  for (int kt = 0; kt < 16; ++kt) {
    const int k0 = kt * 64;
    // stage A (64x64): 2 rounds of 256 lanes x 16B
    gload16(&A[(size_t)(rowBase + sRow) * lda + k0 + sCol], ldsA);
    gload16(&A[(size_t)(rowBase + 32 + sRow) * lda + k0 + sCol], ldsA + 2048);
    // stage B (128x64): 4 rounds; W row-major [4096][1024] is B^T directly
    gload16(&W[(size_t)(colBase + sRow) * DD + k0 + sCol], ldsB);
    gload16(&W[(size_t)(colBase + 32 + sRow) * DD + k0 + sCol], ldsB + 2048);
    gload16(&W[(size_t)(colBase + 64 + sRow) * DD + k0 + sCol], ldsB + 4096);
    gload16(&W[(size_t)(colBase + 96 + sRow) * DD + k0 + sCol], ldsB + 6144);
    __syncthreads();  // compiler drains vmcnt before s_barrier
#pragma unroll
    for (int kk = 0; kk < 2; ++kk) {
      const int ak = kk * 32 + lhi * 8;
      f16x8 af[4], bf[2];
#pragma unroll
      for (int mf = 0; mf < 4; ++mf)
        af[mf] = *(const f16x8*)&As[(mf * 16 + l15) * 64 + ak];
#pragma unroll
      for (int nf = 0; nf < 2; ++nf)
        bf[nf] = *(const f16x8*)&Bs[(wave * 32 + nf * 16 + l15) * 64 + ak];
#pragma unroll
      for (int mf = 0; mf < 4; ++mf)
#pragma unroll
        for (int nf = 0; nf < 2; ++nf)
          acc[mf][nf] = __builtin_amdgcn_mfma_f32_16x16x32_f16(
              af[mf], bf[nf], acc[mf][nf], 0, 0, 0);
    }
    __syncthreads();
  }
  // epilogue: C/D layout col=lane&15, row=(lane>>4)*4+reg  [m89-verified]
#pragma unroll
  for (int mf = 0; mf < 4; ++mf)
#pragma unroll
    for (int nf = 0; nf < 2; ++nf) {
      const int col = colBase + wave * 32 + nf * 16 + l15;
      const size_t row0 = rowBase + mf * 16 + lhi * 4;
#pragma unroll
      for (int r = 0; r < 4; ++r)
        Out[(row0 + r) * NG + col] = (OutT)acc[mf][nf][r];
    }
}

// ---------------------------------------------------------------------------
// Kernel C: elementwise LSTM cell. MODE 0: g = covT*M + bias (t=0, c0=0).
// MODE 1: g = G(fp32) + covT*M + bias. Writes c (fp32), h (fp16 into h_all).
// ---------------------------------------------------------------------------
template <int MODE>
__global__ __launch_bounds__(256) void lstm_ew(
    const float* __restrict__ G, const _Float16* __restrict__ M,
    const float* __restrict__ covT, int t, const float* __restrict__ b_ih,
    const float* __restrict__ b_hh, float* __restrict__ cbuf,
    _Float16* __restrict__ hout)  // hout = h16 + t*HH, row stride TS*HH
{
  const int b = blockIdx.x;
  const int j = threadIdx.x * 4;
  const float a = covT[b * TS + t];
  float g4[4][4];
#pragma unroll
  for (int p = 0; p < 4; ++p) {
    const int off = b * NG + p * HH + j;
    f16x4 mv = *(const f16x4*)&M[off];
    float4 bi = *(const float4*)&b_ih[p * HH + j];
    float4 bh = *(const float4*)&b_hh[p * HH + j];
    const float bia[4] = {bi.x + bh.x, bi.y + bh.y, bi.z + bh.z, bi.w + bh.w};
    if (MODE == 0) {
#pragma unroll
      for (int q = 0; q < 4; ++q) g4[p][q] = a * (float)mv[q] + bia[q];
    } else {
      float4 gv = *(const float4*)&G[off];
      const float ga[4] = {gv.x, gv.y, gv.z, gv.w};
#pragma unroll
      for (int q = 0; q < 4; ++q)
        g4[p][q] = ga[q] + a * (float)mv[q] + bia[q];
    }
  }
  float cov[4] = {0.f, 0.f, 0.f, 0.f};
  if (MODE == 1) {
    float4 co = *(const float4*)&cbuf[b * HH + j];
    cov[0] = co.x; cov[1] = co.y; cov[2] = co.z; cov[3] = co.w;
  }
  float cna[4];
  f16x4 hv;
#pragma unroll
  for (int q = 0; q < 4; ++q) {
    const float i_ = sigm_(g4[0][q]), f_ = sigm_(g4[1][q]);
    const float g_ = tanh_(g4[2][q]), o_ = sigm_(g4[3][q]);
    const float c_ = (MODE == 1 ? f_ * cov[q] : 0.f) + i_ * g_;
    cna[q] = c_;
    hv[q] = (_Float16)(o_ * tanh_(c_));
  }
  *(float4*)&cbuf[b * HH + j] = make_float4(cna[0], cna[1], cna[2], cna[3]);
  *(f16x4*)&hout[(size_t)b * TS * HH + j] = hv;
}

// ---------------------------------------------------------------------------
// Kernel D: softmax over t + temporal attention, reading fp16 h_all.
// ---------------------------------------------------------------------------
__global__ __launch_bounds__(256) void finale(
    const _Float16* __restrict__ h16, const float* __restrict__ attn_W,
    const float* __restrict__ attn_b, float* __restrict__ out) {
  const int b = blockIdx.x, tid = threadIdx.x;
  const f16x4* hb = (const f16x4*)(h16 + (size_t)b * TS * HH);
  float v[TS][4];
#pragma unroll
  for (int t = 0; t < TS; t++) {
    f16x4 hv = hb[t * 256 + tid];
#pragma unroll
    for (int q = 0; q < 4; q++) v[t][q] = (float)hv[q];
  }
  const float4 aw = ((const float4*)attn_W)[tid];
  const float awa[4] = {aw.x, aw.y, aw.z, aw.w};

  float4 outv[TS];
#pragma unroll
  for (int q = 0; q < 4; q++) {
    float m = -1e30f;
#pragma unroll
    for (int t = 0; t < TS; t++) m = fmaxf(m, v[t][q]);
    float e[TS], s = 0.f;
#pragma unroll
    for (int t = 0; t < TS; t++) {
      e[t] = __expf(v[t][q] - m);
      s += e[t];
    }
    const float inv = 1.f / s;
#pragma unroll
    for (int t = 0; t < TS; t++) ((float*)&outv[t])[q] = e[t] * inv;
  }
#pragma unroll
  for (int t = 0; t < TS; t++)
    ((float4*)out)[(size_t)b * TS * 256 + t * 256 + tid] = outv[t];

  float pt[TS];
#pragma unroll
  for (int t = 0; t < TS; t++) {
    pt[t] = tanh_(v[t][0]) * awa[0] + tanh_(v[t][1]) * awa[1] +
            tanh_(v[t][2]) * awa[2] + tanh_(v[t][3]) * awa[3];
  }
#pragma unroll
  for (int t = 0; t < TS; t++)
    for (int m = 32; m >= 1; m >>= 1) pt[t] += __shfl_xor(pt[t], m);
  __shared__ float red[4][TS];
  const int wave = tid >> 6, lane = tid & 63;
  if (lane == 0) {
#pragma unroll
    for (int t = 0; t < TS; t++) red[wave][t] = pt[t];
  }
  __syncthreads();
  if (tid < TS) {
    float s = red[0][tid] + red[1][tid] + red[2][tid] + red[3][tid];
    out[(size_t)BSZ * TS * HH + b * TS + tid] = sigm_(s + attn_b[0]);
  }
}

// ---------------------------------------------------------------------------
extern "C" void kernel_launch(void* const* d_in, const int* in_sizes, int n_in,
                              void* d_out, int out_size, void* d_ws,
                              size_t ws_size, hipStream_t stream) {
  const float* x = (const float*)d_in[0];
  const float* xsh = (const float*)d_in[1];
  const float* W_ih = (const float*)d_in[2];
  const float* W_hh = (const float*)d_in[3];
  const float* b_ih = (const float*)d_in[4];
  const float* b_hh = (const float*)d_in[5];
  const float* attn_W = (const float*)d_in[6];
  const float* attn_b = (const float*)d_in[7];
  float* out = (float*)d_out;
  float* w = (float*)d_ws;

  // workspace layout (fp32 words), total ~50.0 MB.
  // pG (fp32 G, 4M words) aliases covC16 (0.5M) + Wih16 (2M) + 1.5M tail;
  // both are dead before the first G write (gemm t=1).
  float* covT = w;                     // 8192 words
  float* pG = w + 8192;                // 4M words: fp32 G [1024][4096]
  _Float16* covC16 = (_Float16*)pG;            // 1M f16 (dead after gemm0)
  _Float16* Wih16 = (_Float16*)(pG + 524288);  // 4M f16 (dead after gemm0)
  float* pWhh = pG + 4194304;          // 2M words (4M f16)
  float* pM = pWhh + 2097152;          // 2M words (4M f16, lives all steps)
  float* pC = pM + 2097152;            // 1M words fp32 c
  float* pH = pC + 1048576;            // 3.5M words (7M f16 h_all)
  _Float16* Whh16 = (_Float16*)pWhh;
  _Float16* M16 = (_Float16*)pM;
  float* cbuf = pC;
  _Float16* h16 = (_Float16*)pH;       // [B][TS][HH]

  f32_to_f16<<<512, 256, 0, stream>>>(W_ih, Wih16, NG * DD / 4);
  f32_to_f16<<<512, 256, 0, stream>>>(W_hh, Whh16, NG * HH / 4);
  cov_kernel<<<dim3(BSZ), dim3(256), 0, stream>>>(x, xsh, covT, covC16);

  // M = covC @ W_ih^T  (fp16 out: |M| ~ 3e-3, cast error negligible)
  gemm_f16<_Float16><<<dim3(32, 16), dim3(256), 0, stream>>>(covC16, DD, Wih16,
                                                             M16);
  lstm_ew<0><<<dim3(BSZ), dim3(256), 0, stream>>>(nullptr, M16, covT, 0, b_ih,
                                                  b_hh, cbuf, h16);
  for (int t = 1; t < TS; t++) {
    // G = h_{t-1} @ W_hh^T  (fp32 out: precision hedge)
    gemm_f16<float><<<dim3(32, 16), dim3(256), 0, stream>>>(
        h16 + (size_t)(t - 1) * HH, TS * HH, Whh16, pG);
    lstm_ew<1><<<dim3(BSZ), dim3(256), 0, stream>>>(
        pG, M16, covT, t, b_ih, b_hh, cbuf, h16 + (size_t)t * HH);
  }
  finale<<<dim3(BSZ), dim3(256), 0, stream>>>(h16, attn_W, attn_b, out);
}

// Round 9
// 255.151 us; speedup vs baseline: 4.3562x; 1.3544x over previous
//
#include <hip/hip_runtime.h>
#include <math.h>

#define BSZ 1024
#define TS 7
#define DD 1024
#define HH 1024
#define NG 4096  // 4*H

typedef _Float16 f16x8 __attribute__((ext_vector_type(8)));
typedef _Float16 f16x4 __attribute__((ext_vector_type(4)));
typedef float f32x4 __attribute__((ext_vector_type(4)));

__device__ __forceinline__ float sigm_(float x) { return 1.f / (1.f + __expf(-x)); }
__device__ __forceinline__ float tanh_(float x) { return 1.f - 2.f / (__expf(2.f * x) + 1.f); }

__device__ __forceinline__ void gload16(const _Float16* g, _Float16* l) {
  __builtin_amdgcn_global_load_lds(
      (const __attribute__((address_space(1))) void*)g,
      (__attribute__((address_space(3))) void*)l, 16, 0, 0);
}

// ---------------------------------------------------------------------------
// fp32 -> fp16 conversion for both weight matrices in one launch.
// ---------------------------------------------------------------------------
__global__ __launch_bounds__(256) void conv_w(const float* __restrict__ wih,
                                              const float* __restrict__ whh,
                                              _Float16* __restrict__ o_ih,
                                              _Float16* __restrict__ o_hh) {
  const int N4 = NG * DD / 4;  // per matrix
  for (int i = blockIdx.x * 256 + threadIdx.x; i < 2 * N4;
       i += gridDim.x * 256) {
    const float4 v = (i < N4) ? ((const float4*)wih)[i] : ((const float4*)whh)[i - N4];
    f16x4 o;
    o[0] = (_Float16)v.x; o[1] = (_Float16)v.y;
    o[2] = (_Float16)v.z; o[3] = (_Float16)v.w;
    if (i < N4) ((f16x4*)o_ih)[i] = o;
    else        ((f16x4*)o_hh)[i - N4] = o;
  }
}

// ---------------------------------------------------------------------------
// Kernel A: per-batch covariance stats. covT fp32 [B][TS]; covC fp16 [B][DD].
// ---------------------------------------------------------------------------
__global__ __launch_bounds__(256) void cov_kernel(
    const float* __restrict__ x, const float* __restrict__ xsh,
    float* __restrict__ covT, _Float16* __restrict__ covC16) {
  const int b = blockIdx.x, tid = threadIdx.x;
  const float4* xb = (const float4*)(x + (size_t)b * TS * DD);
  const float4* yb = (const float4*)(xsh + (size_t)b * TS * DD);
  float4 xv[TS], yv[TS];
#pragma unroll
  for (int t = 0; t < TS; t++) {
    xv[t] = xb[t * 256 + tid];
    yv[t] = yb[t * 256 + tid];
  }
  f16x4 cc;
#pragma unroll
  for (int q = 0; q < 4; q++) {
    float sx = 0.f, sy = 0.f, sxy = 0.f;
#pragma unroll
    for (int t = 0; t < TS; t++) {
      float a = ((const float*)&xv[t])[q];
      float c = ((const float*)&yv[t])[q];
      sx += a; sy += c; sxy += a * c;
    }
    float v = (sxy - sx * sy * (1.f / TS)) * (1.f / DD);
    cc[q] = (_Float16)(v > 0.f ? v : 0.f);
  }
  *(f16x4*)&covC16[(size_t)b * DD + tid * 4] = cc;

  float psx[TS], psy[TS], psxy[TS];
#pragma unroll
  for (int t = 0; t < TS; t++) {
    float4 a = xv[t], c = yv[t];
    psx[t] = a.x + a.y + a.z + a.w;
    psy[t] = c.x + c.y + c.z + c.w;
    psxy[t] = a.x * c.x + a.y * c.y + a.z * c.z + a.w * c.w;
  }
#pragma unroll
  for (int t = 0; t < TS; t++) {
    for (int m = 32; m >= 1; m >>= 1) {
      psx[t] += __shfl_xor(psx[t], m);
      psy[t] += __shfl_xor(psy[t], m);
      psxy[t] += __shfl_xor(psxy[t], m);
    }
  }
  __shared__ float red[3][4][TS];
  const int wave = tid >> 6, lane = tid & 63;
  if (lane == 0) {
#pragma unroll
    for (int t = 0; t < TS; t++) {
      red[0][wave][t] = psx[t];
      red[1][wave][t] = psy[t];
      red[2][wave][t] = psxy[t];
    }
  }
  __syncthreads();
  if (tid < TS) {
    float sx = red[0][0][tid] + red[0][1][tid] + red[0][2][tid] + red[0][3][tid];
    float sy = red[1][0][tid] + red[1][1][tid] + red[1][2][tid] + red[1][3][tid];
    float sxy = red[2][0][tid] + red[2][1][tid] + red[2][2][tid] + red[2][3][tid];
    float v = (sxy - sx * sy * (1.f / DD)) * (1.f / TS);
    covT[b * TS + tid] = v > 0.f ? v : 0.f;
  }
}

// ---------------------------------------------------------------------------
// Kernel B: fused GEMM + LSTM cell, one launch per timestep.
//   acc = A @ W^T on the 4 gate strips (cols n = gate*32 + jj),
//   then cross-wave LDS gate exchange + cell math in-epilogue.
// Tile BM=64 x (4 gates x 32 j), BK=64, 256 thr / 4 waves (wave = gate).
// 2-phase prefetch (stage k+1 before compute k, one barrier/iter).
// XOR-swizzled LDS via pre-swizzled GLOBAL source (gload_lds dest linear).
//   MODE 0: A=covC16, W=W_ih; writes M16; cell with c0=0, g=a*acc+bias.
//   MODE 1: A=h_{t-1},  W=W_hh; reads M16;  g=acc+a*M+bias.
// ---------------------------------------------------------------------------
template <int MODE>
__global__ __launch_bounds__(256) void fused_step(
    const _Float16* __restrict__ A, int lda, const _Float16* __restrict__ W,
    const float* __restrict__ covT, int t, _Float16* __restrict__ M16,
    const float* __restrict__ b_ih, const float* __restrict__ b_hh,
    float* __restrict__ cbuf, _Float16* __restrict__ hout)  // h16 + t*HH
{
  __shared__ __align__(16) char smem[49152];
  _Float16* As0 = (_Float16*)smem;             // 64x64 f16, 8 KB
  _Float16* Bs0 = (_Float16*)(smem + 8192);    // 128x64 f16, 16 KB
  _Float16* As1 = (_Float16*)(smem + 24576);
  _Float16* Bs1 = (_Float16*)(smem + 32768);
  float* gls = (float*)smem;  // epilogue overlay: [4][64][33] f32, 33 KB

  const int tid = threadIdx.x;
  const int wave = tid >> 6, lane = tid & 63;
  const int l15 = lane & 15, lhi = lane >> 4;
  const int rowBase = blockIdx.y * 64;   // batch rows
  const int jBase = blockIdx.x * 32;     // j-tile (32 hidden cols)
  const int sRow = tid >> 3;             // 0..31 staging row
  const int sColSw = (((tid & 7) ^ (sRow & 7)) * 8);  // pre-swizzled k-chunk
  const int ldsOff = (tid & ~63) * 8;    // wave-uniform gload dest offset

  f32x4 acc[4][2] = {};

  // ---- staging: A 2 rounds, B 4 gate strips (rows g*HH + jBase + sRow) ----
#define STAGE(as, bs, kt)                                                     \
  {                                                                           \
    const int k0 = (kt)*64;                                                   \
    gload16(&A[(size_t)(rowBase + sRow) * lda + k0 + sColSw], (as) + ldsOff); \
    gload16(&A[(size_t)(rowBase + 32 + sRow) * lda + k0 + sColSw],            \
            (as) + 2048 + ldsOff);                                            \
    gload16(&W[(size_t)(0 * HH + jBase + sRow) * DD + k0 + sColSw],           \
            (bs) + 0 + ldsOff);                                               \
    gload16(&W[(size_t)(1 * HH + jBase + sRow) * DD + k0 + sColSw],           \
            (bs) + 2048 + ldsOff);                                            \
    gload16(&W[(size_t)(2 * HH + jBase + sRow) * DD + k0 + sColSw],           \
            (bs) + 4096 + ldsOff);                                            \
    gload16(&W[(size_t)(3 * HH + jBase + sRow) * DD + k0 + sColSw],           \
            (bs) + 6144 + ldsOff);                                            \
  }

  // ---- compute one K-tile from LDS (swizzled read addresses) ----
#define COMPUTE(as, bs)                                                       \
  {                                                                           \
    _Pragma("unroll") for (int kk = 0; kk < 2; ++kk) {                        \
      const int akx = (kk * 32 + lhi * 8) ^ ((l15 & 7) << 3);                 \
      f16x8 af[4], bf[2];                                                     \
      _Pragma("unroll") for (int mf = 0; mf < 4; ++mf) af[mf] =               \
          *(const f16x8*)&(as)[(mf * 16 + l15) * 64 + akx];                   \
      _Pragma("unroll") for (int nf = 0; nf < 2; ++nf) bf[nf] =               \
          *(const f16x8*)&(bs)[(wave * 32 + nf * 16 + l15) * 64 + akx];       \
      _Pragma("unroll") for (int mf = 0; mf < 4; ++mf)                        \
          _Pragma("unroll") for (int nf = 0; nf < 2; ++nf) acc[mf][nf] =      \
              __builtin_amdgcn_mfma_f32_16x16x32_f16(af[mf], bf[nf],          \
                                                     acc[mf][nf], 0, 0, 0);   \
    }                                                                         \
  }

  STAGE(As0, Bs0, 0);
  __syncthreads();
#pragma unroll
  for (int kt = 0; kt < 16; kt += 2) {
    STAGE(As1, Bs1, kt + 1);   // prefetch next (in flight during compute)
    COMPUTE(As0, Bs0);
    __syncthreads();           // drains prefetch + guards As0 reuse
    if (kt + 2 < 16) STAGE(As0, Bs0, kt + 2);
    COMPUTE(As1, Bs1);
    __syncthreads();
  }

  // ---- epilogue: gate exchange through LDS (wave = gate) ----
#pragma unroll
  for (int mf = 0; mf < 4; ++mf)
#pragma unroll
    for (int nf = 0; nf < 2; ++nf)
#pragma unroll
      for (int r = 0; r < 4; ++r)
        gls[(wave * 64 + mf * 16 + lhi * 4 + r) * 33 + nf * 16 + l15] =
            acc[mf][nf][r];
  __syncthreads();

  // thread owns jj = tid&31 (fixed), rows k*8 + (tid>>5), k=0..7
  const int jj = tid & 31;
  const int j = jBase + jj;
  float bia[4];
#pragma unroll
  for (int g = 0; g < 4; ++g) bia[g] = b_ih[g * HH + j] + b_hh[g * HH + j];

#pragma unroll
  for (int k = 0; k < 8; ++k) {
    const int row = k * 8 + (tid >> 5);
    const int b = rowBase + row;
    const float a = covT[b * TS + t];
    float pre[4];
#pragma unroll
    for (int g = 0; g < 4; ++g) {
      const float gv = gls[(g * 64 + row) * 33 + jj];
      if (MODE == 0) {
        M16[(size_t)b * NG + g * HH + j] = (_Float16)gv;
        pre[g] = a * gv + bia[g];
      } else {
        pre[g] = gv + a * (float)M16[(size_t)b * NG + g * HH + j] + bia[g];
      }
    }
    const float i_ = sigm_(pre[0]), f_ = sigm_(pre[1]);
    const float g_ = tanh_(pre[2]), o_ = sigm_(pre[3]);
    const float c_ =
        (MODE == 1 ? f_ * cbuf[(size_t)b * HH + j] : 0.f) + i_ * g_;
    cbuf[(size_t)b * HH + j] = c_;
    hout[(size_t)b * TS * HH + j] = (_Float16)(o_ * tanh_(c_));
  }
#undef STAGE
#undef COMPUTE
}

// ---------------------------------------------------------------------------
// Kernel D: softmax over t + temporal attention, reading fp16 h_all.
// ---------------------------------------------------------------------------
__global__ __launch_bounds__(256) void finale(
    const _Float16* __restrict__ h16, const float* __restrict__ attn_W,
    const float* __restrict__ attn_b, float* __restrict__ out) {
  const int b = blockIdx.x, tid = threadIdx.x;
  const f16x4* hb = (const f16x4*)(h16 + (size_t)b * TS * HH);
  float v[TS][4];
#pragma unroll
  for (int t = 0; t < TS; t++) {
    f16x4 hv = hb[t * 256 + tid];
#pragma unroll
    for (int q = 0; q < 4; q++) v[t][q] = (float)hv[q];
  }
  const float4 aw = ((const float4*)attn_W)[tid];
  const float awa[4] = {aw.x, aw.y, aw.z, aw.w};

  float4 outv[TS];
#pragma unroll
  for (int q = 0; q < 4; q++) {
    float m = -1e30f;
#pragma unroll
    for (int t = 0; t < TS; t++) m = fmaxf(m, v[t][q]);
    float e[TS], s = 0.f;
#pragma unroll
    for (int t = 0; t < TS; t++) {
      e[t] = __expf(v[t][q] - m);
      s += e[t];
    }
    const float inv = 1.f / s;
#pragma unroll
    for (int t = 0; t < TS; t++) ((float*)&outv[t])[q] = e[t] * inv;
  }
#pragma unroll
  for (int t = 0; t < TS; t++)
    ((float4*)out)[(size_t)b * TS * 256 + t * 256 + tid] = outv[t];

  float pt[TS];
#pragma unroll
  for (int t = 0; t < TS; t++) {
    pt[t] = tanh_(v[t][0]) * awa[0] + tanh_(v[t][1]) * awa[1] +
            tanh_(v[t][2]) * awa[2] + tanh_(v[t][3]) * awa[3];
  }
#pragma unroll
  for (int t = 0; t < TS; t++)
    for (int m = 32; m >= 1; m >>= 1) pt[t] += __shfl_xor(pt[t], m);
  __shared__ float red[4][TS];
  const int wave = tid >> 6, lane = tid & 63;
  if (lane == 0) {
#pragma unroll
    for (int t = 0; t < TS; t++) red[wave][t] = pt[t];
  }
  __syncthreads();
  if (tid < TS) {
    float s = red[0][tid] + red[1][tid] + red[2][tid] + red[3][tid];
    out[(size_t)BSZ * TS * HH + b * TS + tid] = sigm_(s + attn_b[0]);
  }
}

// ---------------------------------------------------------------------------
extern "C" void kernel_launch(void* const* d_in, const int* in_sizes, int n_in,
                              void* d_out, int out_size, void* d_ws,
                              size_t ws_size, hipStream_t stream) {
  const float* x = (const float*)d_in[0];
  const float* xsh = (const float*)d_in[1];
  const float* W_ih = (const float*)d_in[2];
  const float* W_hh = (const float*)d_in[3];
  const float* b_ih = (const float*)d_in[4];
  const float* b_hh = (const float*)d_in[5];
  const float* attn_W = (const float*)d_in[6];
  const float* attn_b = (const float*)d_in[7];
  float* out = (float*)d_out;
  float* w = (float*)d_ws;

  // workspace (fp32 words), total ~42 MB, no aliasing
  float* covT = w;                      // 8192
  _Float16* covC16 = (_Float16*)(w + 8192);        // 1M f16 (0.5M words)
  _Float16* Wih16 = (_Float16*)(w + 532480);       // 4M f16 (2M words)
  _Float16* Whh16 = (_Float16*)(w + 2629632);      // 4M f16 (2M words)
  _Float16* M16 = (_Float16*)(w + 4726784);        // 4M f16 (2M words)
  float* cbuf = w + 6823936;                       // 1M words fp32
  _Float16* h16 = (_Float16*)(w + 7872512);        // 7M f16 (3.5M words)

  conv_w<<<1024, 256, 0, stream>>>(W_ih, W_hh, Wih16, Whh16);
  cov_kernel<<<dim3(BSZ), dim3(256), 0, stream>>>(x, xsh, covT, covC16);

  // t = 0: M = covC @ W_ih^T fused with first cell (c0 = 0)
  fused_step<0><<<dim3(32, 16), dim3(256), 0, stream>>>(
      covC16, DD, Wih16, covT, 0, M16, b_ih, b_hh, cbuf, h16);
  for (int t = 1; t < TS; t++) {
    fused_step<1><<<dim3(32, 16), dim3(256), 0, stream>>>(
        h16 + (size_t)(t - 1) * HH, TS * HH, Whh16, covT, t, M16, b_ih, b_hh,
        cbuf, h16 + (size_t)t * HH);
  }
  finale<<<dim3(BSZ), dim3(256), 0, stream>>>(h16, attn_W, attn_b, out);
}